// Round 8
// baseline (1371.075 us; speedup 1.0000x reference)
//
#include <hip/hip_runtime.h>
#include <math.h>

constexpr int NANCH = 3136;           // 28*28*4
constexpr float SCORE_T = 0.7f;
constexpr float IOU_T = 0.3f;
constexpr int MAXP = 10;

typedef unsigned short u16;
typedef __attribute__((ext_vector_type(8))) short short8x;
typedef __attribute__((ext_vector_type(4))) float f32x4;

__device__ inline u16 f2bf(float f) {          // RNE float->bf16
  unsigned u = __builtin_bit_cast(unsigned, f);
  u += 0x7fffu + ((u >> 16) & 1u);
  return (u16)(u >> 16);
}
__device__ inline float bf2f(u16 h) {
  unsigned u = ((unsigned)h) << 16;
  return __builtin_bit_cast(float, u);
}

// =====================================================================
// Weight prep for 4-cin convs: [COUT][4][3][3] fp32 -> [cout][K=64] bf16
// hi/lo planes, K = tap*4 + cin, zero-padded 36..63.
// =====================================================================
__global__ __launch_bounds__(256) void w1prep_k(const float* __restrict__ w,
                                                u16* __restrict__ hi, u16* __restrict__ lo,
                                                int COUT) {
  const int i = blockIdx.x * 256 + threadIdx.x;
  if (i >= COUT * 64) return;
  const int k = i & 63, co = i >> 6;
  float v = 0.f;
  if (k < 36) { const int tap = k >> 2, cin = k & 3; v = w[co * 36 + cin * 9 + tap]; }
  const u16 h = f2bf(v);
  hi[i] = h;
  lo[i] = f2bf(v - bf2f(h));
}

// =====================================================================
// 4-cin 3x3 conv via im2col MFMA (K = 36 padded to 64).
// Block: 4 rows x 16 cols of one image; 4 waves.
// MODE 0 (CLM c1): plain bf16, COUT=64, BN+ReLU -> NHWC bf16 out.
// MODE 1 (RPN conv1): hi/lo x hi/lo (3 products), COUT=32,
//                     BN + affine-max-pool2x2 + ReLU -> NHWC hi/lo out.
// =====================================================================
template<int MODE>
__global__ __launch_bounds__(256) void c1mfma_k(
    const float* __restrict__ x,             // [*,4,224,224] fp32
    const u16* __restrict__ wfh, const u16* __restrict__ wfl,
    const float* __restrict__ bias, const float* __restrict__ gamma,
    const float* __restrict__ beta,
    u16* __restrict__ outhi, u16* __restrict__ outlo) {
  constexpr int COUT = MODE ? 32 : 64;
  constexpr int NF   = MODE ? 2 : 4;
  constexpr int PS   = MODE ? 136 : 72;      // patch row stride (shorts), 16B-aligned
  __shared__ u16 s_patch[64 * PS];
  __shared__ u16 s_wh[COUT * 72];
  __shared__ u16 s_wl[MODE ? COUT * 72 : 8];
  __shared__ float s_raw[4 * 6 * 18];
  __shared__ float s_pool[MODE ? 4 * 16 * 17 : 1];
  __shared__ u16 s_out[MODE ? 8 : 64 * 72];

  const int tid = threadIdx.x, lane = tid & 63, w = tid >> 6;
  const int lr = lane & 15, lg = lane >> 4;
  const int img = blockIdx.z;
  const int x0 = blockIdx.x * 16, y0 = blockIdx.y * 4;

  // zero K-pad regions of s_patch (36..63, and 100..127 for lo)
  for (int i = tid; i < 64 * 7; i += 256) {
    const int p = i / 7, q = i % 7;
    *(uint2*)&s_patch[p * PS + 36 + q * 4] = make_uint2(0, 0);
    if (MODE) *(uint2*)&s_patch[p * PS + 100 + q * 4] = make_uint2(0, 0);
  }
  // stage raw input 4cin x 6 x 18 (zero halo)
  for (int i = tid; i < 432; i += 256) {
    const int cin = i / 108, r = i % 108;
    const int ry = r / 18, rx = r % 18;
    const int gy = y0 - 1 + ry, gx = x0 - 1 + rx;
    float v = 0.f;
    if ((unsigned)gy < 224u && (unsigned)gx < 224u)
      v = x[(((size_t)img * 4 + cin) * 224 + gy) * 224 + gx];
    s_raw[i] = v;
  }
  // stage weights
  for (int i = tid; i < COUT * 8; i += 256) {
    const int co = i >> 3, q = i & 7;
    *(uint4*)&s_wh[co * 72 + q * 8] = *(const uint4*)&wfh[co * 64 + q * 8];
    if (MODE) *(uint4*)&s_wl[co * 72 + q * 8] = *(const uint4*)&wfl[co * 64 + q * 8];
  }
  __syncthreads();

  // build im2col patches
  for (int i = tid; i < 576; i += 256) {
    const int p = i / 9, tap = i % 9;
    const int ty = p >> 4, tx = p & 15;
    const int ky = tap / 3, kx = tap % 3;
    u16 h4[4], l4[4];
#pragma unroll
    for (int cin = 0; cin < 4; cin++) {
      const float v = s_raw[cin * 108 + (ty + ky) * 18 + (tx + kx)];
      h4[cin] = f2bf(v);
      if (MODE) l4[cin] = f2bf(v - bf2f(h4[cin]));
    }
    *(uint2*)&s_patch[p * PS + tap * 4] = *(uint2*)h4;
    if (MODE) *(uint2*)&s_patch[p * PS + 64 + tap * 4] = *(uint2*)l4;
  }
  __syncthreads();

  // MFMA: A pixel index for this lane
  int pA;
  if (MODE) pA = ((w >> 1) * 2 + (lr >> 3)) * 16 + (w & 1) * 8 + (lr & 7);
  else      pA = w * 16 + lr;

  f32x4 acc[NF];
#pragma unroll
  for (int nf = 0; nf < NF; nf++) acc[nf] = (f32x4)(0.f);

#pragma unroll
  for (int ks = 0; ks < 2; ks++) {
    const short8x ah = *(const short8x*)&s_patch[pA * PS + ks * 32 + lg * 8];
    short8x al;
    if (MODE) al = *(const short8x*)&s_patch[pA * PS + 64 + ks * 32 + lg * 8];
#pragma unroll
    for (int nf = 0; nf < NF; nf++) {
      const short8x bh = *(const short8x*)&s_wh[(nf * 16 + lr) * 72 + ks * 32 + lg * 8];
      if (MODE) {
        const short8x bl = *(const short8x*)&s_wl[(nf * 16 + lr) * 72 + ks * 32 + lg * 8];
        acc[nf] = __builtin_amdgcn_mfma_f32_16x16x32_bf16(al, bh, acc[nf], 0, 0, 0);
        acc[nf] = __builtin_amdgcn_mfma_f32_16x16x32_bf16(ah, bl, acc[nf], 0, 0, 0);
      }
      acc[nf] = __builtin_amdgcn_mfma_f32_16x16x32_bf16(ah, bh, acc[nf], 0, 0, 0);
    }
  }

  const float rsq = 1.f / sqrtf(1.f + 1e-5f);

  if (MODE == 0) {   // BN+ReLU -> s_out -> coalesced NHWC bf16
#pragma unroll
    for (int nf = 0; nf < 4; nf++) {
      const int co = nf * 16 + lr;
      const float bi = bias[co], scl = gamma[co] * rsq, shf = beta[co];
#pragma unroll
      for (int j = 0; j < 4; j++) {
        const float e = fmaxf((acc[nf][j] + bi) * scl + shf, 0.f);
        s_out[(w * 16 + lg * 4 + j) * 72 + co] = f2bf(e);
      }
    }
    __syncthreads();
    for (int i = tid; i < 512; i += 256) {
      const int p = i >> 3, q = i & 7;
      const int oy = y0 + (p >> 4), ox = x0 + (p & 15);
      *(uint4*)&outhi[(((size_t)img * 224 + oy) * 224 + ox) * 64 + q * 8] =
          *(uint4*)&s_out[p * 72 + q * 8];
    }
  } else {           // affine -> 2x2 maxpool -> ReLU -> NHWC hi/lo
#pragma unroll
    for (int nf = 0; nf < 2; nf++) {
      const int co = nf * 16 + lr;
      const float bi = bias[co], scl = gamma[co] * rsq, shf = beta[co];
#pragma unroll
      for (int j = 0; j < 4; j++) {
        const int m = lg * 4 + j;
        s_pool[w * 272 + m * 17 + lr] = (acc[nf][j] + bi) * scl + shf;
      }
      __syncthreads();
      {
        const int pc = lane >> 4, n = lane & 15;
        const float* sp = &s_pool[w * 272];
        float m0 = fmaxf(sp[(pc * 2) * 17 + n], sp[(pc * 2 + 1) * 17 + n]);
        float m1 = fmaxf(sp[(pc * 2 + 8) * 17 + n], sp[(pc * 2 + 9) * 17 + n]);
        const float mm = fmaxf(fmaxf(m0, m1), 0.f);
        const int py = (y0 >> 1) + (w >> 1), px = (x0 >> 1) + (w & 1) * 4 + pc;
        const size_t o = (((size_t)img * 112 + py) * 112 + px) * 32 + nf * 16 + n;
        const u16 h = f2bf(mm);
        outhi[o] = h; outlo[o] = f2bf(mm - bf2f(h));
      }
      __syncthreads();
    }
  }
}

// =====================================================================
// Weight prep: [COUT][CIN][3][3] fp32 -> [tap][cout][cin] bf16 hi/lo planes
// =====================================================================
__global__ __launch_bounds__(256) void wsplit_k(const float* __restrict__ w,
                                                u16* __restrict__ hi, u16* __restrict__ lo,
                                                int COUT, int CIN) {
  const int n = 9 * COUT * CIN;
  const int i = blockIdx.x * 256 + threadIdx.x;
  if (i >= n) return;
  const int cin = i % CIN; int r = i / CIN;
  const int cout = r % COUT; const int tap = r / COUT;
  const float v = w[((size_t)cout * CIN + cin) * 9 + tap];
  const u16 h = f2bf(v);
  hi[i] = h; lo[i] = f2bf(v - bf2f(h));
}

// single-plane bf16 prep for CLM c2: [128,64,3,3] -> [tap][128][64]
__global__ __launch_bounds__(256) void w2b_k(const float* __restrict__ w,
                                             u16* __restrict__ wb) {
  const int i = blockIdx.x * 256 + threadIdx.x;   // 73728
  if (i >= 73728) return;
  const int cin = i & 63; const int r = i >> 6;
  const int cout = r & 127; const int tap = r >> 7;
  wb[i] = f2bf(w[(((size_t)cout * 64 + cin) * 3 + tap / 3) * 3 + tap % 3]);
}

// =====================================================================
// Split-bf16 MFMA 3x3 conv (fp32-accurate via hi/lo x hi/lo, 3 products).
// Input NHWC hi/lo planes. Block: 4-row x 32-col band, 64 couts.
// POOL: fused BN+ReLU+2x2 maxpool, NHWC hi/lo out.
// !POOL: +bias+ReLU, NHWC fp32 out (rpn final conv).
// =====================================================================
template<int CINCH, bool POOL, bool BN>
__global__ __launch_bounds__(256) void sconv_k(
    const u16* __restrict__ ahi, const u16* __restrict__ alo,
    const u16* __restrict__ whi, const u16* __restrict__ wlo,
    const float* __restrict__ bias, const float* __restrict__ gamma,
    const float* __restrict__ beta,
    u16* __restrict__ ohi, u16* __restrict__ olo, float* __restrict__ of32,
    int H, int W, int COUT, int cog) {
  __shared__ u16 s_in[6 * 34 * 72];   // [row][col][hi32|lo32], col stride 72
  __shared__ u16 s_w[64 * 72];        // [cout][hi32|lo32]
  const int tid = threadIdx.x, lane = tid & 63, wave = tid >> 6;
  const int wm = wave >> 1, wn = wave & 1, lr = lane & 15, lg = lane >> 4;
  const int img = blockIdx.z / cog, co0 = (blockIdx.z % cog) * 64;
  const int x0 = blockIdx.x * 32, band = blockIdx.y;
  const int CIN = CINCH * 32;

  f32x4 acc[4][2];
#pragma unroll
  for (int mi = 0; mi < 4; ++mi) { acc[mi][0] = (f32x4)(0.f); acc[mi][1] = (f32x4)(0.f); }

  for (int cc2 = 0; cc2 < CINCH; ++cc2) {
    // stage 6 rows x 34 cols x (32hi + 32lo) cin
    for (int idx = tid; idx < 1632; idx += 256) {
      const int r = idx / 272, rem = idx % 272;
      const int c = rem >> 3, q = rem & 7, pl = q >> 2, qq = q & 3;
      const int gy = band * 4 - 1 + r, gx = x0 - 1 + c;
      uint4 v = make_uint4(0, 0, 0, 0);
      if ((unsigned)gy < (unsigned)H && (unsigned)gx < (unsigned)W) {
        const u16* src = pl ? alo : ahi;
        v = *(const uint4*)(src + ((size_t)(img * H + gy) * W + gx) * CIN + cc2 * 32 + qq * 8);
      }
      *(uint4*)(&s_in[(r * 34 + c) * 72 + pl * 32 + qq * 8]) = v;
    }
    for (int tap = 0; tap < 9; ++tap) {
      const int ky = tap / 3, kx = tap % 3;
      for (int idx = tid; idx < 512; idx += 256) {
        const int cout = idx >> 3, q = idx & 7, pl = q >> 2, qq = q & 3;
        const u16* src = pl ? wlo : whi;
        uint4 v = *(const uint4*)(src + ((size_t)tap * COUT + co0 + cout) * CIN + cc2 * 32 + qq * 8);
        *(uint4*)(&s_w[cout * 72 + pl * 32 + qq * 8]) = v;
      }
      __syncthreads();
      short8x ah[4], al[4], bh[2], bl[2];
#pragma unroll
      for (int mi = 0; mi < 4; ++mi) {
        const int base = ((2 * wm + (mi >> 1) + ky) * 34 + (mi & 1) * 16 + lr + kx) * 72;
        ah[mi] = *(const short8x*)(&s_in[base + lg * 8]);
        al[mi] = *(const short8x*)(&s_in[base + 32 + lg * 8]);
      }
#pragma unroll
      for (int ni = 0; ni < 2; ++ni) {
        const int wb2 = (wn * 32 + ni * 16 + lr) * 72;
        bh[ni] = *(const short8x*)(&s_w[wb2 + lg * 8]);
        bl[ni] = *(const short8x*)(&s_w[wb2 + 32 + lg * 8]);
      }
#pragma unroll
      for (int mi = 0; mi < 4; ++mi)
#pragma unroll
        for (int ni = 0; ni < 2; ++ni) {
          acc[mi][ni] = __builtin_amdgcn_mfma_f32_16x16x32_bf16(al[mi], bh[ni], acc[mi][ni], 0, 0, 0);
          acc[mi][ni] = __builtin_amdgcn_mfma_f32_16x16x32_bf16(ah[mi], bl[ni], acc[mi][ni], 0, 0, 0);
          acc[mi][ni] = __builtin_amdgcn_mfma_f32_16x16x32_bf16(ah[mi], bh[ni], acc[mi][ni], 0, 0, 0);
        }
      __syncthreads();
    }
  }

  const float rsq = 1.f / sqrtf(1.f + 1e-5f);
#pragma unroll
  for (int ni = 0; ni < 2; ++ni) {
    const int cout = co0 + wn * 32 + ni * 16 + lr;
    const float bi = bias[cout];
    const float scl = BN ? gamma[cout] * rsq : 1.f;
    const float shf = BN ? beta[cout] : 0.f;
    if (POOL) {
      const int OH = H >> 1, OW = W >> 1;
      const int py = band * 2 + wm;
#pragma unroll
      for (int ch = 0; ch < 2; ++ch)
#pragma unroll
        for (int jp = 0; jp < 2; ++jp) {
          float m = (acc[ch][ni][2 * jp] + bi) * scl + shf;
          m = fmaxf(m, (acc[ch][ni][2 * jp + 1] + bi) * scl + shf);
          m = fmaxf(m, (acc[ch + 2][ni][2 * jp] + bi) * scl + shf);
          m = fmaxf(m, (acc[ch + 2][ni][2 * jp + 1] + bi) * scl + shf);
          m = fmaxf(m, 0.f);
          const int px = (x0 >> 1) + ch * 8 + lg * 2 + jp;
          if (px < OW) {
            const size_t o = ((size_t)(img * OH + py) * OW + px) * COUT + cout;
            const u16 h = f2bf(m);
            ohi[o] = h; olo[o] = f2bf(m - bf2f(h));
          }
        }
    } else {
#pragma unroll
      for (int mi = 0; mi < 4; ++mi) {
        const int row = band * 4 + 2 * wm + (mi >> 1);
#pragma unroll
        for (int j = 0; j < 4; ++j) {
          const int px = x0 + (mi & 1) * 16 + lg * 4 + j;
          if (px < W)
            of32[((size_t)(img * H + row) * W + px) * COUT + cout] =
                fmaxf(acc[mi][ni][j] + bi, 0.f);
        }
      }
    }
  }
}

// =====================================================================
// CLM conv2 MFMA v2, band-per-block. B-operand loaded straight from L2
// into registers per tap (no weight LDS, 1 barrier per block).
// Pool epilogue: shfl_xor reduce over lg, per-wave LDS slots, one
// cross-wave reduce, one global atomicAdd per cout (pooled pre-zeroed).
// =====================================================================
__global__ __launch_bounds__(256, 3) void c2band_k(
    const u16* __restrict__ act, const u16* __restrict__ wb,
    const float* __restrict__ bias, const float* __restrict__ gamma,
    const float* __restrict__ beta, float* __restrict__ pooled, int gimg0) {
  __shared__ u16 s_in[6 * 34 * 72];
  __shared__ float s_wp[256];

  const int tid = threadIdx.x;
  const int lane = tid & 63, wave = tid >> 6;
  const int wm = wave >> 1, wn = wave & 1;
  const int lr = lane & 15, lg = lane >> 4;
  const int img = blockIdx.z >> 3, band = blockIdx.z & 7;
  const int x0 = blockIdx.x * 32, y0 = blockIdx.y * 32;
  const float rsq = 1.f / sqrtf(1.f + 1e-5f);

  // stage input band (6 rows x 34 cols x 64 cin, zero halo)
  for (int idx = tid; idx < 1632; idx += 256) {
    const int r = idx / 272, rem = idx % 272;
    const int c = rem >> 3, q = rem & 7;
    const int gy = y0 + band * 4 - 1 + r, gx = x0 - 1 + c;
    uint4 v = make_uint4(0, 0, 0, 0);
    if ((unsigned)gy < 224u && (unsigned)gx < 224u)
      v = *(const uint4*)(act + (((size_t)img * 224 + gy) * 224 + gx) * 64 + q * 8);
    *(uint4*)(&s_in[(r * 34 + c) * 72 + q * 8]) = v;
  }
  __syncthreads();

  f32x4 acc[4][4];
#pragma unroll
  for (int mi = 0; mi < 4; ++mi)
#pragma unroll
    for (int ni = 0; ni < 4; ++ni) acc[mi][ni] = (f32x4)(0.f);

  // per-lane B base: wb[tap][cout][cin64]; this lane reads cout=wn*64+ni*16+lr,
  // cin window h*32 + lg*8
  const u16* wbase = wb + ((size_t)(wn * 64 + lr)) * 64 + lg * 8;

#pragma unroll
  for (int tap = 0; tap < 9; ++tap) {
    const int ky = tap / 3, kx = tap % 3;
    short8x bfr[2][4];
#pragma unroll
    for (int h = 0; h < 2; ++h)
#pragma unroll
      for (int ni = 0; ni < 4; ++ni)
        bfr[h][ni] = *(const short8x*)(wbase + tap * 8192 + ni * 1024 + h * 32);
#pragma unroll
    for (int h = 0; h < 2; ++h) {
      short8x a[4];
#pragma unroll
      for (int mi = 0; mi < 4; ++mi) {
        const int rl = wm * 2 + (mi >> 1) + ky;
        const int cc = (mi & 1) * 16 + lr + kx;
        a[mi] = *(const short8x*)(&s_in[(rl * 34 + cc) * 72 + h * 32 + lg * 8]);
      }
#pragma unroll
      for (int mi = 0; mi < 4; ++mi)
#pragma unroll
        for (int ni = 0; ni < 4; ++ni)
          acc[mi][ni] = __builtin_amdgcn_mfma_f32_16x16x32_bf16(a[mi], bfr[h][ni], acc[mi][ni], 0, 0, 0);
    }
  }

  // epilogue: bias+BN+ReLU, reduce over this thread's 16 px, then over lg,
  // then over waves sharing the same cout half.
  float part[4];
#pragma unroll
  for (int ni = 0; ni < 4; ++ni) {
    const int co = wn * 64 + ni * 16 + lr;
    const float bi = bias[co], scl = gamma[co] * rsq, shf = beta[co];
    float s = 0.f;
#pragma unroll
    for (int mi = 0; mi < 4; ++mi)
#pragma unroll
      for (int j = 0; j < 4; ++j)
        s += fmaxf((acc[mi][ni][j] + bi) * scl + shf, 0.f);
    s += __shfl_xor(s, 16);
    s += __shfl_xor(s, 32);
    part[ni] = s;
  }
  if (lane < 16) {
#pragma unroll
    for (int ni = 0; ni < 4; ++ni)
      s_wp[wave * 64 + ni * 16 + lr] = part[ni];
  }
  __syncthreads();
  if (tid < 128) {
    const int w0 = tid >> 6, idx = tid & 63;
    const float v = s_wp[w0 * 64 + idx] + s_wp[(w0 + 2) * 64 + idx];
    atomicAdd(&pooled[(size_t)(gimg0 + img) * 6272 + tid * 49 + blockIdx.y * 7 + blockIdx.x],
              v * (1.f / 1024.f));
  }
}

// =====================================================================
// RPN head: feat NHWC [B,784,256]. 1x1 cls/reg + softmax + decode.
// =====================================================================
__global__ __launch_bounds__(256) void rpn_head_k(
    const float* __restrict__ feat,
    const float* __restrict__ clsw, const float* __restrict__ clsb,
    const float* __restrict__ regw, const float* __restrict__ regb,
    float* __restrict__ probs, float* __restrict__ boxes) {
  const int gid = blockIdx.x * 256 + threadIdx.x;
  if (gid >= 32 * NANCH) return;
  const int a = gid & 3;
  int r = gid >> 2;
  const int x = r % 28; r /= 28;
  const int y = r % 28;
  const int b = r / 28;

  const float* f = feat + ((size_t)b * 784 + y * 28 + x) * 256;
  float c0 = clsb[2 * a], c1 = clsb[2 * a + 1];
  float r0 = regb[4 * a], r1 = regb[4 * a + 1], r2 = regb[4 * a + 2], r3 = regb[4 * a + 3];
#pragma unroll 4
  for (int c = 0; c < 256; c++) {
    const float fv = f[c];
    c0 = fmaf(fv, clsw[(2 * a) * 256 + c], c0);
    c1 = fmaf(fv, clsw[(2 * a + 1) * 256 + c], c1);
    r0 = fmaf(fv, regw[(4 * a) * 256 + c], r0);
    r1 = fmaf(fv, regw[(4 * a + 1) * 256 + c], r1);
    r2 = fmaf(fv, regw[(4 * a + 2) * 256 + c], r2);
    r3 = fmaf(fv, regw[(4 * a + 3) * 256 + c], r3);
  }
  const float p = 1.f / (1.f + expf(c0 - c1));

  const float cx = (x + 0.5f) * (1.f / 28.f);
  const float cy = (y + 0.5f) * (1.f / 28.f);
  const float sz = (float)(16 << a) * (1.f / 224.f);
  const float ncx = cx + r0 * 0.1f, ncy = cy + r1 * 0.1f;
  const float nw = sz * expf(r2 * 0.2f), nh = sz * expf(r3 * 0.2f);
  const float x1 = fminf(fmaxf(ncx - nw * 0.5f, 0.f), 1.f);
  const float y1 = fminf(fmaxf(ncy - nh * 0.5f, 0.f), 1.f);
  const float x2 = fminf(fmaxf(ncx + nw * 0.5f, 0.f), 1.f);
  const float y2 = fminf(fmaxf(ncy + nh * 0.5f, 0.f), 1.f);

  probs[gid] = p;
  ((float4*)boxes)[gid] = make_float4(x1, y1, x2, y2);
}

// =====================================================================
// Greedy NMS, one block per image (matches jax.lax.scan semantics).
// =====================================================================
__global__ __launch_bounds__(256) void nms_k(
    const float* __restrict__ probs, const float* __restrict__ boxes,
    float* __restrict__ dout, int* __restrict__ hasflag) {
  const int b = blockIdx.x;
  const int t = threadIdx.x;
  __shared__ float sc[NANCH];
  __shared__ float ar[NANCH];
  __shared__ float4 bx[NANCH];
  __shared__ float rv[256];
  __shared__ int   ri[256];
  __shared__ int s_any, s_sel[MAXP], s_ok[MAXP];

  if (t == 0) s_any = 0;
  __syncthreads();

  int anyl = 0;
  for (int i = t; i < NANCH; i += 256) {
    const float p = probs[(size_t)b * NANCH + i];
    const float4 bb = ((const float4*)boxes)[(size_t)b * NANCH + i];
    bx[i] = bb;
    ar[i] = (bb.z - bb.x) * (bb.w - bb.y);
    sc[i] = (p > SCORE_T) ? p : -INFINITY;
    if (p > SCORE_T) anyl = 1;
  }
  if (anyl) atomicOr(&s_any, 1);
  __syncthreads();

  for (int it = 0; it < MAXP; ++it) {
    float bv = -INFINITY; int bi = 0x7fffffff;
    for (int i = t; i < NANCH; i += 256) {
      const float v = sc[i];
      if (v > bv || (v == bv && i < bi)) { bv = v; bi = i; }
    }
    rv[t] = bv; ri[t] = bi;
    __syncthreads();
    for (int st = 128; st > 0; st >>= 1) {
      if (t < st) {
        const float ov = rv[t + st]; const int oi = ri[t + st];
        if (ov > rv[t] || (ov == rv[t] && oi < ri[t])) { rv[t] = ov; ri[t] = oi; }
      }
      __syncthreads();
    }
    if (t == 0) { s_sel[it] = ri[0]; s_ok[it] = (rv[0] > -INFINITY) ? 1 : 0; }
    __syncthreads();
    const int sel = s_sel[it];
    const int ok  = s_ok[it];
    if (ok) {
      const float4 bs = bx[sel]; const float as = ar[sel];
      for (int i = t; i < NANCH; i += 256) {
        const float xx1 = fmaxf(bs.x, bx[i].x), yy1 = fmaxf(bs.y, bx[i].y);
        const float xx2 = fminf(bs.z, bx[i].z), yy2 = fminf(bs.w, bx[i].w);
        const float inter = fmaxf(xx2 - xx1, 0.f) * fmaxf(yy2 - yy1, 0.f);
        const float iou = inter / (as + ar[i] - inter);
        if (iou > IOU_T || i == sel) sc[i] = -INFINITY;
      }
    }
    __syncthreads();
  }

  if (t < MAXP) {
    const int sel = s_ok[t] ? s_sel[t] : 0;
    const float okf = s_ok[t] ? 1.f : 0.f;
    const float4 bb = bx[sel];
    float* kb = dout + 64;
    float* ks = dout + 64 + 32 * MAXP * 4;
    float* ko = dout + 64 + 32 * MAXP * 5;
    const size_t base = ((size_t)b * MAXP + t) * 4;
    kb[base + 0] = bb.x * okf; kb[base + 1] = bb.y * okf;
    kb[base + 2] = bb.z * okf; kb[base + 3] = bb.w * okf;
    ks[b * MAXP + t] = probs[(size_t)b * NANCH + sel] * okf;
    ko[b * MAXP + t] = okf;
  }
  if (t == 0) hasflag[b] = s_any;
}

// =====================================================================
// FC split-K: weights read exactly once across the grid.
// =====================================================================
__global__ __launch_bounds__(64) void fcsplit_k(
    const float* __restrict__ x, const float* __restrict__ w,
    float* __restrict__ part, int K, int N, int kchunk) {
  extern __shared__ float sx[];
  const int o = blockIdx.x * 64 + threadIdx.x;
  const int k0 = blockIdx.y * kchunk;
  for (int i = threadIdx.x; i < 32 * kchunk; i += 64) {
    const int bb = i / kchunk, kk = i % kchunk;
    sx[i] = x[(size_t)bb * K + k0 + kk];
  }
  __syncthreads();
  float acc[32];
#pragma unroll
  for (int bb = 0; bb < 32; bb++) acc[bb] = 0.f;
#pragma unroll 8
  for (int kk = 0; kk < kchunk; kk++) {
    const float wv = w[(size_t)(k0 + kk) * N + o];
#pragma unroll
    for (int bb = 0; bb < 32; bb++) acc[bb] = fmaf(sx[bb * kchunk + kk], wv, acc[bb]);
  }
  float* p = part + (size_t)blockIdx.y * 32 * N + o;
#pragma unroll
  for (int bb = 0; bb < 32; bb++) p[(size_t)bb * N] = acc[bb];
}

__global__ __launch_bounds__(256) void fcreduce_k(
    const float* __restrict__ part, const float* __restrict__ bias,
    float* __restrict__ y, int N, int KT, int dorelu) {
  const int i = blockIdx.x * 256 + threadIdx.x;
  if (i >= 32 * N) return;
  const int o = i % N;
  float s = bias[o];
  for (int kt = 0; kt < KT; kt++) s += part[(size_t)kt * 32 * N + i];
  y[i] = dorelu ? fmaxf(s, 0.f) : s;
}

__global__ __launch_bounds__(64) void final_k(
    const float* __restrict__ f3, const float* __restrict__ w,
    const float* __restrict__ bi, const int* __restrict__ hasflag,
    float* __restrict__ dout) {
  const int t = threadIdx.x;
  if (t >= 64) return;
  const int b = t >> 1, j = t & 1;
  float acc = bi[j];
#pragma unroll 4
  for (int k = 0; k < 128; k++) acc = fmaf(f3[b * 128 + k], w[k * 2 + j], acc);
  dout[b * 2 + j] = hasflag[b] ? acc : (j == 0 ? 1.f : 0.f);
}

// =====================================================================
extern "C" void kernel_launch(void* const* d_in, const int* in_sizes, int n_in,
                              void* d_out, int out_size, void* d_ws, size_t ws_size,
                              hipStream_t stream) {
  const float* x    = (const float*)d_in[0];
  const float* r1w  = (const float*)d_in[1];  const float* r1b = (const float*)d_in[2];
  const float* g1   = (const float*)d_in[3];  const float* b1  = (const float*)d_in[4];
  const float* r2w  = (const float*)d_in[5];  const float* r2b = (const float*)d_in[6];
  const float* g2   = (const float*)d_in[7];  const float* b2  = (const float*)d_in[8];
  const float* r3w  = (const float*)d_in[9];  const float* r3b = (const float*)d_in[10];
  const float* g3   = (const float*)d_in[11]; const float* b3  = (const float*)d_in[12];
  const float* rpw  = (const float*)d_in[13]; const float* rpb = (const float*)d_in[14];
  const float* clsw = (const float*)d_in[15]; const float* clsb = (const float*)d_in[16];
  const float* regw = (const float*)d_in[17]; const float* regb = (const float*)d_in[18];
  const float* c1w  = (const float*)d_in[19]; const float* c1b = (const float*)d_in[20];
  const float* cg1  = (const float*)d_in[21]; const float* cb1 = (const float*)d_in[22];
  const float* c2w  = (const float*)d_in[23]; const float* c2b = (const float*)d_in[24];
  const float* cg2  = (const float*)d_in[25]; const float* cb2 = (const float*)d_in[26];
  const float* fc1w = (const float*)d_in[27]; const float* fc1b = (const float*)d_in[28];
  const float* fc2w = (const float*)d_in[29]; const float* fc2b = (const float*)d_in[30];
  const float* fc3w = (const float*)d_in[31]; const float* fc3b = (const float*)d_in[32];
  const float* fc4w = (const float*)d_in[33]; const float* fc4b = (const float*)d_in[34];
  float* dout = (float*)d_out;
  float* Wp = (float*)d_ws;

  // ---- workspace layout (float slots) ----
  const size_t o_h1   = 0;                      // hi/lo NHWC 32x112x112x32: 2x12.85M shorts
  const size_t o_h2   = 12845056;               // hi/lo NHWC 32x56x56x64
  const size_t o_h3   = o_h2 + 6422528;         // hi/lo NHWC 32x28x28x128
  const size_t o_prob = o_h3 + 3211264;
  const size_t o_box  = o_prob + 100352;
  const size_t o_flag = o_box + 401408;
  const size_t o_pool = o_flag + 32;
  const size_t o_f1   = o_pool + 200704;
  const size_t o_f2   = o_f1 + 16384;
  const size_t o_f3   = o_f2 + 8192;
  const size_t o_w2b  = o_f3 + 4096;            // 73728 shorts (CLM c2 bf16)
  const size_t o_w2s  = o_w2b + 36864;          // conv2 hi+lo: 2x18432 shorts
  const size_t o_w3s  = o_w2s + 18432;          // conv3 hi+lo: 2x73728 shorts
  const size_t o_wps  = o_w3s + 73728;          // rpw  hi+lo: 2x294912 shorts
  const size_t o_w1r  = o_wps + 294912;         // rpn conv1 [32][64] hi+lo: 2x2048 shorts
  const size_t o_w1c  = o_w1r + 2048;           // clm c1 [64][64] hi+lo: 2x4096 shorts

  u16* h1hi = (u16*)(Wp + o_h1); u16* h1lo = h1hi + 12845056;
  u16* h2hi = (u16*)(Wp + o_h2); u16* h2lo = h2hi + 6422528;
  u16* h3hi = (u16*)(Wp + o_h3); u16* h3lo = h3hi + 3211264;
  float* probs = Wp + o_prob; float* boxes = Wp + o_box;
  int* hasflag = (int*)(Wp + o_flag);
  float* pooled = Wp + o_pool;
  float* f1 = Wp + o_f1; float* f2 = Wp + o_f2; float* f3 = Wp + o_f3;
  u16* w2b  = (u16*)(Wp + o_w2b);
  u16* w2hi = (u16*)(Wp + o_w2s); u16* w2lo = w2hi + 18432;
  u16* w3hi = (u16*)(Wp + o_w3s); u16* w3lo = w3hi + 73728;
  u16* wphi = (u16*)(Wp + o_wps); u16* wplo = wphi + 294912;
  u16* w1rhi = (u16*)(Wp + o_w1r); u16* w1rlo = w1rhi + 2048;
  u16* w1chi = (u16*)(Wp + o_w1c); u16* w1clo = w1chi + 4096;
  // aliases over dead h1 region (safe by stream order):
  float* h4f32 = Wp + o_h1;            // rpn feat NHWC fp32 [32,784,256] = 6.42M
  u16*   c1buf = (u16*)(Wp + o_h1);    // CLM c1 NHWC bf16, 8 imgs = 25.69M shorts
  float* fcpart = Wp + o_h1;           // fc split partials (<= 1.05M)

  // ---- weight prep ----
  wsplit_k<<<(9 * 64 * 32 + 255) / 256, 256, 0, stream>>>(r2w, w2hi, w2lo, 64, 32);
  wsplit_k<<<(9 * 128 * 64 + 255) / 256, 256, 0, stream>>>(r3w, w3hi, w3lo, 128, 64);
  wsplit_k<<<(9 * 256 * 128 + 255) / 256, 256, 0, stream>>>(rpw, wphi, wplo, 256, 128);
  w2b_k<<<288, 256, 0, stream>>>(c2w, w2b);
  w1prep_k<<<8, 256, 0, stream>>>(r1w, w1rhi, w1rlo, 32);
  w1prep_k<<<16, 256, 0, stream>>>(c1w, w1chi, w1clo, 64);

  // ---- Stage 1: RPN backbone ----
  c1mfma_k<1><<<dim3(14, 56, 32), 256, 0, stream>>>(
      x, w1rhi, w1rlo, r1b, g1, b1, h1hi, h1lo);
  sconv_k<1, true, true><<<dim3(4, 28, 32), 256, 0, stream>>>(
      h1hi, h1lo, w2hi, w2lo, r2b, g2, b2, h2hi, h2lo, nullptr, 112, 112, 64, 1);
  sconv_k<2, true, true><<<dim3(2, 14, 64), 256, 0, stream>>>(
      h2hi, h2lo, w3hi, w3lo, r3b, g3, b3, h3hi, h3lo, nullptr, 56, 56, 128, 2);
  sconv_k<4, false, false><<<dim3(1, 7, 128), 256, 0, stream>>>(
      h3hi, h3lo, wphi, wplo, rpb, rpb, rpb, nullptr, nullptr, h4f32, 28, 28, 256, 4);

  rpn_head_k<<<(32 * NANCH + 255) / 256, 256, 0, stream>>>(h4f32, clsw, clsb, regw, regb, probs, boxes);
  nms_k<<<32, 256, 0, stream>>>(probs, boxes, dout, hasflag);

  // ---- Stage 2: CLM ----
  hipMemsetAsync(pooled, 0, 32 * 6272 * sizeof(float), stream);
  constexpr int CHUNK = 8;
  for (int c0 = 0; c0 < 32; c0 += CHUNK) {
    c1mfma_k<0><<<dim3(14, 56, CHUNK), 256, 0, stream>>>(
        x + (size_t)c0 * 4 * 224 * 224, w1chi, w1clo, c1b, cg1, cb1, c1buf, nullptr);
    c2band_k<<<dim3(7, 7, CHUNK * 8), 256, 0, stream>>>(
        c1buf, w2b, c2b, cg2, cb2, pooled, c0);
  }

  // ---- FC head ----
  fcsplit_k<<<dim3(8, 64), 64, 32 * 98 * 4, stream>>>(pooled, fc1w, fcpart, 6272, 512, 98);
  fcreduce_k<<<64, 256, 0, stream>>>(fcpart, fc1b, f1, 512, 64, 1);
  fcsplit_k<<<dim3(4, 16), 64, 32 * 32 * 4, stream>>>(f1, fc2w, fcpart, 512, 256, 32);
  fcreduce_k<<<32, 256, 0, stream>>>(fcpart, fc2b, f2, 256, 16, 1);
  fcsplit_k<<<dim3(2, 8), 64, 32 * 32 * 4, stream>>>(f2, fc3w, fcpart, 256, 128, 32);
  fcreduce_k<<<16, 256, 0, stream>>>(fcpart, fc3b, f3, 128, 8, 1);
  final_k<<<1, 64, 0, stream>>>(f3, fc4w, fc4b, hasflag, dout);
}

// Round 10
// 1097.518 us; speedup vs baseline: 1.2493x; 1.2493x over previous
//
#include <hip/hip_runtime.h>
#include <math.h>

constexpr int NANCH = 3136;           // 28*28*4
constexpr float SCORE_T = 0.7f;
constexpr float IOU_T = 0.3f;
constexpr int MAXP = 10;

typedef unsigned short u16;
typedef __attribute__((ext_vector_type(8))) short short8x;
typedef __attribute__((ext_vector_type(4))) float f32x4;

__device__ inline u16 f2bf(float f) {          // RNE float->bf16
  unsigned u = __builtin_bit_cast(unsigned, f);
  u += 0x7fffu + ((u >> 16) & 1u);
  return (u16)(u >> 16);
}
__device__ inline float bf2f(u16 h) {
  unsigned u = ((unsigned)h) << 16;
  return __builtin_bit_cast(float, u);
}

// =====================================================================
// Weight prep for 4-cin convs: [COUT][4][3][3] fp32 -> [cout][K=64] bf16
// hi/lo planes, K = tap*4 + cin, zero-padded 36..63.
// =====================================================================
__global__ __launch_bounds__(256) void w1prep_k(const float* __restrict__ w,
                                                u16* __restrict__ hi, u16* __restrict__ lo,
                                                int COUT) {
  const int i = blockIdx.x * 256 + threadIdx.x;
  if (i >= COUT * 64) return;
  const int k = i & 63, co = i >> 6;
  float v = 0.f;
  if (k < 36) { const int tap = k >> 2, cin = k & 3; v = w[co * 36 + cin * 9 + tap]; }
  const u16 h = f2bf(v);
  hi[i] = h;
  lo[i] = f2bf(v - bf2f(h));
}

// =====================================================================
// 4-cin 3x3 conv via im2col MFMA (K = 36 padded to 64).
// Block: 4 rows x 16 cols of one image; 4 waves.
// MODE 0 (CLM c1): plain bf16, COUT=64, BN+ReLU -> NHWC bf16 out.
// MODE 1 (RPN conv1): hi/lo x hi/lo (3 products), COUT=32,
//                     BN + affine-max-pool2x2 + ReLU -> NHWC hi/lo out.
// =====================================================================
template<int MODE>
__global__ __launch_bounds__(256) void c1mfma_k(
    const float* __restrict__ x,             // [*,4,224,224] fp32
    const u16* __restrict__ wfh, const u16* __restrict__ wfl,
    const float* __restrict__ bias, const float* __restrict__ gamma,
    const float* __restrict__ beta,
    u16* __restrict__ outhi, u16* __restrict__ outlo) {
  constexpr int COUT = MODE ? 32 : 64;
  constexpr int NF   = MODE ? 2 : 4;
  constexpr int PS   = MODE ? 136 : 72;      // patch row stride (shorts), 16B-aligned
  __shared__ u16 s_patch[64 * PS];
  __shared__ u16 s_wh[COUT * 72];
  __shared__ u16 s_wl[MODE ? COUT * 72 : 8];
  __shared__ float s_raw[4 * 6 * 18];
  __shared__ float s_pool[MODE ? 4 * 16 * 17 : 1];
  __shared__ u16 s_out[MODE ? 8 : 64 * 72];

  const int tid = threadIdx.x, lane = tid & 63, w = tid >> 6;
  const int lr = lane & 15, lg = lane >> 4;
  const int img = blockIdx.z;
  const int x0 = blockIdx.x * 16, y0 = blockIdx.y * 4;

  // zero K-pad regions of s_patch (36..63, and 100..127 for lo)
  for (int i = tid; i < 64 * 7; i += 256) {
    const int p = i / 7, q = i % 7;
    *(uint2*)&s_patch[p * PS + 36 + q * 4] = make_uint2(0, 0);
    if (MODE) *(uint2*)&s_patch[p * PS + 100 + q * 4] = make_uint2(0, 0);
  }
  // stage raw input 4cin x 6 x 18 (zero halo)
  for (int i = tid; i < 432; i += 256) {
    const int cin = i / 108, r = i % 108;
    const int ry = r / 18, rx = r % 18;
    const int gy = y0 - 1 + ry, gx = x0 - 1 + rx;
    float v = 0.f;
    if ((unsigned)gy < 224u && (unsigned)gx < 224u)
      v = x[(((size_t)img * 4 + cin) * 224 + gy) * 224 + gx];
    s_raw[i] = v;
  }
  // stage weights
  for (int i = tid; i < COUT * 8; i += 256) {
    const int co = i >> 3, q = i & 7;
    *(uint4*)&s_wh[co * 72 + q * 8] = *(const uint4*)&wfh[co * 64 + q * 8];
    if (MODE) *(uint4*)&s_wl[co * 72 + q * 8] = *(const uint4*)&wfl[co * 64 + q * 8];
  }
  __syncthreads();

  // build im2col patches
  for (int i = tid; i < 576; i += 256) {
    const int p = i / 9, tap = i % 9;
    const int ty = p >> 4, tx = p & 15;
    const int ky = tap / 3, kx = tap % 3;
    u16 h4[4], l4[4];
#pragma unroll
    for (int cin = 0; cin < 4; cin++) {
      const float v = s_raw[cin * 108 + (ty + ky) * 18 + (tx + kx)];
      h4[cin] = f2bf(v);
      if (MODE) l4[cin] = f2bf(v - bf2f(h4[cin]));
    }
    *(uint2*)&s_patch[p * PS + tap * 4] = *(uint2*)h4;
    if (MODE) *(uint2*)&s_patch[p * PS + 64 + tap * 4] = *(uint2*)l4;
  }
  __syncthreads();

  // MFMA: A pixel index for this lane
  int pA;
  if (MODE) pA = ((w >> 1) * 2 + (lr >> 3)) * 16 + (w & 1) * 8 + (lr & 7);
  else      pA = w * 16 + lr;

  f32x4 acc[NF];
#pragma unroll
  for (int nf = 0; nf < NF; nf++) acc[nf] = (f32x4)(0.f);

#pragma unroll
  for (int ks = 0; ks < 2; ks++) {
    const short8x ah = *(const short8x*)&s_patch[pA * PS + ks * 32 + lg * 8];
    short8x al;
    if (MODE) al = *(const short8x*)&s_patch[pA * PS + 64 + ks * 32 + lg * 8];
#pragma unroll
    for (int nf = 0; nf < NF; nf++) {
      const short8x bh = *(const short8x*)&s_wh[(nf * 16 + lr) * 72 + ks * 32 + lg * 8];
      if (MODE) {
        const short8x bl = *(const short8x*)&s_wl[(nf * 16 + lr) * 72 + ks * 32 + lg * 8];
        acc[nf] = __builtin_amdgcn_mfma_f32_16x16x32_bf16(al, bh, acc[nf], 0, 0, 0);
        acc[nf] = __builtin_amdgcn_mfma_f32_16x16x32_bf16(ah, bl, acc[nf], 0, 0, 0);
      }
      acc[nf] = __builtin_amdgcn_mfma_f32_16x16x32_bf16(ah, bh, acc[nf], 0, 0, 0);
    }
  }

  const float rsq = 1.f / sqrtf(1.f + 1e-5f);

  if (MODE == 0) {   // BN+ReLU -> s_out -> coalesced NHWC bf16
#pragma unroll
    for (int nf = 0; nf < 4; nf++) {
      const int co = nf * 16 + lr;
      const float bi = bias[co], scl = gamma[co] * rsq, shf = beta[co];
#pragma unroll
      for (int j = 0; j < 4; j++) {
        const float e = fmaxf((acc[nf][j] + bi) * scl + shf, 0.f);
        s_out[(w * 16 + lg * 4 + j) * 72 + co] = f2bf(e);
      }
    }
    __syncthreads();
    for (int i = tid; i < 512; i += 256) {
      const int p = i >> 3, q = i & 7;
      const int oy = y0 + (p >> 4), ox = x0 + (p & 15);
      *(uint4*)&outhi[(((size_t)img * 224 + oy) * 224 + ox) * 64 + q * 8] =
          *(uint4*)&s_out[p * 72 + q * 8];
    }
  } else {           // affine -> 2x2 maxpool -> ReLU -> NHWC hi/lo
#pragma unroll
    for (int nf = 0; nf < 2; nf++) {
      const int co = nf * 16 + lr;
      const float bi = bias[co], scl = gamma[co] * rsq, shf = beta[co];
#pragma unroll
      for (int j = 0; j < 4; j++) {
        const int m = lg * 4 + j;
        s_pool[w * 272 + m * 17 + lr] = (acc[nf][j] + bi) * scl + shf;
      }
      __syncthreads();
      {
        const int pc = lane >> 4, n = lane & 15;
        const float* sp = &s_pool[w * 272];
        float m0 = fmaxf(sp[(pc * 2) * 17 + n], sp[(pc * 2 + 1) * 17 + n]);
        float m1 = fmaxf(sp[(pc * 2 + 8) * 17 + n], sp[(pc * 2 + 9) * 17 + n]);
        const float mm = fmaxf(fmaxf(m0, m1), 0.f);
        const int py = (y0 >> 1) + (w >> 1), px = (x0 >> 1) + (w & 1) * 4 + pc;
        const size_t o = (((size_t)img * 112 + py) * 112 + px) * 32 + nf * 16 + n;
        const u16 h = f2bf(mm);
        outhi[o] = h; outlo[o] = f2bf(mm - bf2f(h));
      }
      __syncthreads();
    }
  }
}

// =====================================================================
// Weight prep: [COUT][CIN][3][3] fp32 -> [tap][cout][cin] bf16 hi/lo planes
// =====================================================================
__global__ __launch_bounds__(256) void wsplit_k(const float* __restrict__ w,
                                                u16* __restrict__ hi, u16* __restrict__ lo,
                                                int COUT, int CIN) {
  const int n = 9 * COUT * CIN;
  const int i = blockIdx.x * 256 + threadIdx.x;
  if (i >= n) return;
  const int cin = i % CIN; int r = i / CIN;
  const int cout = r % COUT; const int tap = r / COUT;
  const float v = w[((size_t)cout * CIN + cin) * 9 + tap];
  const u16 h = f2bf(v);
  hi[i] = h; lo[i] = f2bf(v - bf2f(h));
}

// single-plane bf16 prep for CLM c2: [128,64,3,3] -> [tap][128][64]
__global__ __launch_bounds__(256) void w2b_k(const float* __restrict__ w,
                                             u16* __restrict__ wb) {
  const int i = blockIdx.x * 256 + threadIdx.x;   // 73728
  if (i >= 73728) return;
  const int cin = i & 63; const int r = i >> 6;
  const int cout = r & 127; const int tap = r >> 7;
  wb[i] = f2bf(w[(((size_t)cout * 64 + cin) * 3 + tap / 3) * 3 + tap % 3]);
}

// =====================================================================
// Split-bf16 MFMA 3x3 conv (fp32-accurate via hi/lo x hi/lo, 3 products).
// Input NHWC hi/lo planes. Block: 4-row x 32-col band, 64 couts.
// POOL: fused BN+ReLU+2x2 maxpool, NHWC hi/lo out.
// !POOL: +bias+ReLU, NHWC fp32 out (rpn final conv).
// =====================================================================
template<int CINCH, bool POOL, bool BN>
__global__ __launch_bounds__(256) void sconv_k(
    const u16* __restrict__ ahi, const u16* __restrict__ alo,
    const u16* __restrict__ whi, const u16* __restrict__ wlo,
    const float* __restrict__ bias, const float* __restrict__ gamma,
    const float* __restrict__ beta,
    u16* __restrict__ ohi, u16* __restrict__ olo, float* __restrict__ of32,
    int H, int W, int COUT, int cog) {
  __shared__ u16 s_in[6 * 34 * 72];   // [row][col][hi32|lo32], col stride 72
  __shared__ u16 s_w[64 * 72];        // [cout][hi32|lo32]
  const int tid = threadIdx.x, lane = tid & 63, wave = tid >> 6;
  const int wm = wave >> 1, wn = wave & 1, lr = lane & 15, lg = lane >> 4;
  const int img = blockIdx.z / cog, co0 = (blockIdx.z % cog) * 64;
  const int x0 = blockIdx.x * 32, band = blockIdx.y;
  const int CIN = CINCH * 32;

  f32x4 acc[4][2];
#pragma unroll
  for (int mi = 0; mi < 4; ++mi) { acc[mi][0] = (f32x4)(0.f); acc[mi][1] = (f32x4)(0.f); }

  for (int cc2 = 0; cc2 < CINCH; ++cc2) {
    // stage 6 rows x 34 cols x (32hi + 32lo) cin
    for (int idx = tid; idx < 1632; idx += 256) {
      const int r = idx / 272, rem = idx % 272;
      const int c = rem >> 3, q = rem & 7, pl = q >> 2, qq = q & 3;
      const int gy = band * 4 - 1 + r, gx = x0 - 1 + c;
      uint4 v = make_uint4(0, 0, 0, 0);
      if ((unsigned)gy < (unsigned)H && (unsigned)gx < (unsigned)W) {
        const u16* src = pl ? alo : ahi;
        v = *(const uint4*)(src + ((size_t)(img * H + gy) * W + gx) * CIN + cc2 * 32 + qq * 8);
      }
      *(uint4*)(&s_in[(r * 34 + c) * 72 + pl * 32 + qq * 8]) = v;
    }
    for (int tap = 0; tap < 9; ++tap) {
      const int ky = tap / 3, kx = tap % 3;
      for (int idx = tid; idx < 512; idx += 256) {
        const int cout = idx >> 3, q = idx & 7, pl = q >> 2, qq = q & 3;
        const u16* src = pl ? wlo : whi;
        uint4 v = *(const uint4*)(src + ((size_t)tap * COUT + co0 + cout) * CIN + cc2 * 32 + qq * 8);
        *(uint4*)(&s_w[cout * 72 + pl * 32 + qq * 8]) = v;
      }
      __syncthreads();
      short8x ah[4], al[4], bh[2], bl[2];
#pragma unroll
      for (int mi = 0; mi < 4; ++mi) {
        const int base = ((2 * wm + (mi >> 1) + ky) * 34 + (mi & 1) * 16 + lr + kx) * 72;
        ah[mi] = *(const short8x*)(&s_in[base + lg * 8]);
        al[mi] = *(const short8x*)(&s_in[base + 32 + lg * 8]);
      }
#pragma unroll
      for (int ni = 0; ni < 2; ++ni) {
        const int wb2 = (wn * 32 + ni * 16 + lr) * 72;
        bh[ni] = *(const short8x*)(&s_w[wb2 + lg * 8]);
        bl[ni] = *(const short8x*)(&s_w[wb2 + 32 + lg * 8]);
      }
#pragma unroll
      for (int mi = 0; mi < 4; ++mi)
#pragma unroll
        for (int ni = 0; ni < 2; ++ni) {
          acc[mi][ni] = __builtin_amdgcn_mfma_f32_16x16x32_bf16(al[mi], bh[ni], acc[mi][ni], 0, 0, 0);
          acc[mi][ni] = __builtin_amdgcn_mfma_f32_16x16x32_bf16(ah[mi], bl[ni], acc[mi][ni], 0, 0, 0);
          acc[mi][ni] = __builtin_amdgcn_mfma_f32_16x16x32_bf16(ah[mi], bh[ni], acc[mi][ni], 0, 0, 0);
        }
      __syncthreads();
    }
  }

  const float rsq = 1.f / sqrtf(1.f + 1e-5f);
#pragma unroll
  for (int ni = 0; ni < 2; ++ni) {
    const int cout = co0 + wn * 32 + ni * 16 + lr;
    const float bi = bias[cout];
    const float scl = BN ? gamma[cout] * rsq : 1.f;
    const float shf = BN ? beta[cout] : 0.f;
    if (POOL) {
      const int OH = H >> 1, OW = W >> 1;
      const int py = band * 2 + wm;
#pragma unroll
      for (int ch = 0; ch < 2; ++ch)
#pragma unroll
        for (int jp = 0; jp < 2; ++jp) {
          float m = (acc[ch][ni][2 * jp] + bi) * scl + shf;
          m = fmaxf(m, (acc[ch][ni][2 * jp + 1] + bi) * scl + shf);
          m = fmaxf(m, (acc[ch + 2][ni][2 * jp] + bi) * scl + shf);
          m = fmaxf(m, (acc[ch + 2][ni][2 * jp + 1] + bi) * scl + shf);
          m = fmaxf(m, 0.f);
          const int px = (x0 >> 1) + ch * 8 + lg * 2 + jp;
          if (px < OW) {
            const size_t o = ((size_t)(img * OH + py) * OW + px) * COUT + cout;
            const u16 h = f2bf(m);
            ohi[o] = h; olo[o] = f2bf(m - bf2f(h));
          }
        }
    } else {
#pragma unroll
      for (int mi = 0; mi < 4; ++mi) {
        const int row = band * 4 + 2 * wm + (mi >> 1);
#pragma unroll
        for (int j = 0; j < 4; ++j) {
          const int px = x0 + (mi & 1) * 16 + lg * 4 + j;
          if (px < W)
            of32[((size_t)(img * H + row) * W + px) * COUT + cout] =
                fmaxf(acc[mi][ni][j] + bi, 0.f);
        }
      }
    }
  }
}

// =====================================================================
// CLM conv2 MFMA v3, band-per-block. Weights staged in LDS (restored
// from v1 after v2's L2-direct regression) + DOUBLE-BUFFERED: next-tap
// weights are loaded to registers BEFORE the MFMA cluster and ds_written
// to the alternate buffer AFTER it (issue-early/write-late), 1 barrier
// per tap. Pool epilogue via shfl_xor + per-wave LDS + global atomicAdd.
// =====================================================================
__global__ __launch_bounds__(256, 2) void c2band_k(
    const u16* __restrict__ act, const u16* __restrict__ wb,
    const float* __restrict__ bias, const float* __restrict__ gamma,
    const float* __restrict__ beta, float* __restrict__ pooled, int gimg0) {
  __shared__ u16 s_in[6 * 34 * 72];       // 29.4 KB
  __shared__ u16 s_w[2][2 * 128 * 40];    // 2 x 20 KB, [half][cout][cin32->40]
  __shared__ float s_wp[256];

  const int tid = threadIdx.x;
  const int lane = tid & 63, wave = tid >> 6;
  const int wm = wave >> 1, wn = wave & 1;
  const int lr = lane & 15, lg = lane >> 4;
  const int img = blockIdx.z >> 3, band = blockIdx.z & 7;
  const int x0 = blockIdx.x * 32, y0 = blockIdx.y * 32;
  const float rsq = 1.f / sqrtf(1.f + 1e-5f);

  // stage input band (6 rows x 34 cols x 64 cin, zero halo)
  for (int idx = tid; idx < 1632; idx += 256) {
    const int r = idx / 272, rem = idx % 272;
    const int c = rem >> 3, q = rem & 7;
    const int gy = y0 + band * 4 - 1 + r, gx = x0 - 1 + c;
    uint4 v = make_uint4(0, 0, 0, 0);
    if ((unsigned)gy < 224u && (unsigned)gx < 224u)
      v = *(const uint4*)(act + (((size_t)img * 224 + gy) * 224 + gx) * 64 + q * 8);
    *(uint4*)(&s_in[(r * 34 + c) * 72 + q * 8]) = v;
  }

  // per-thread weight-staging slots (4 uint4 = 16 KB per tap across 256 thr)
  uint4 wreg0, wreg1, wreg2, wreg3;
  const int i0 = tid, i1 = tid + 256, i2 = tid + 512, i3 = tid + 768;
#define WLOAD(tap)                                                          \
  {                                                                         \
    wreg0 = *(const uint4*)(wb + ((size_t)(tap) * 128 + (i0 >> 3)) * 64 + (i0 & 7) * 8); \
    wreg1 = *(const uint4*)(wb + ((size_t)(tap) * 128 + (i1 >> 3)) * 64 + (i1 & 7) * 8); \
    wreg2 = *(const uint4*)(wb + ((size_t)(tap) * 128 + (i2 >> 3)) * 64 + (i2 & 7) * 8); \
    wreg3 = *(const uint4*)(wb + ((size_t)(tap) * 128 + (i3 >> 3)) * 64 + (i3 & 7) * 8); \
  }
#define WSTORE(buf)                                                         \
  {                                                                         \
    *(uint4*)(&s_w[buf][((i0 & 7) >> 2) * 5120 + (i0 >> 3) * 40 + (i0 & 3) * 8]) = wreg0; \
    *(uint4*)(&s_w[buf][((i1 & 7) >> 2) * 5120 + (i1 >> 3) * 40 + (i1 & 3) * 8]) = wreg1; \
    *(uint4*)(&s_w[buf][((i2 & 7) >> 2) * 5120 + (i2 >> 3) * 40 + (i2 & 3) * 8]) = wreg2; \
    *(uint4*)(&s_w[buf][((i3 & 7) >> 2) * 5120 + (i3 >> 3) * 40 + (i3 & 3) * 8]) = wreg3; \
  }

  WLOAD(0); WSTORE(0);
  __syncthreads();                 // covers s_in + s_w[0]

  f32x4 acc[4][4];
#pragma unroll
  for (int mi = 0; mi < 4; ++mi)
#pragma unroll
    for (int ni = 0; ni < 4; ++ni) acc[mi][ni] = (f32x4)(0.f);

#pragma unroll
  for (int tap = 0; tap < 9; ++tap) {
    const int cur = tap & 1;
    if (tap < 8) WLOAD(tap + 1);               // issue early
    const int ky = tap / 3, kx = tap % 3;
#pragma unroll
    for (int h = 0; h < 2; ++h) {
      short8x a[4], bf[4];
#pragma unroll
      for (int mi = 0; mi < 4; ++mi) {
        const int rl = wm * 2 + (mi >> 1) + ky;
        const int cc = (mi & 1) * 16 + lr + kx;
        a[mi] = *(const short8x*)(&s_in[(rl * 34 + cc) * 72 + h * 32 + lg * 8]);
      }
#pragma unroll
      for (int ni = 0; ni < 4; ++ni) {
        const int co = wn * 64 + ni * 16 + lr;
        bf[ni] = *(const short8x*)(&s_w[cur][h * 5120 + co * 40 + lg * 8]);
      }
#pragma unroll
      for (int mi = 0; mi < 4; ++mi)
#pragma unroll
        for (int ni = 0; ni < 4; ++ni)
          acc[mi][ni] = __builtin_amdgcn_mfma_f32_16x16x32_bf16(a[mi], bf[ni], acc[mi][ni], 0, 0, 0);
    }
    if (tap < 8) WSTORE(cur ^ 1);              // write late
    __syncthreads();
  }
#undef WLOAD
#undef WSTORE

  // epilogue: bias+BN+ReLU, reduce 16 px/thread, then lg via shfl,
  // then cross-wave (wm) via LDS; one global atomicAdd per cout.
  float part[4];
#pragma unroll
  for (int ni = 0; ni < 4; ++ni) {
    const int co = wn * 64 + ni * 16 + lr;
    const float bi = bias[co], scl = gamma[co] * rsq, shf = beta[co];
    float s = 0.f;
#pragma unroll
    for (int mi = 0; mi < 4; ++mi)
#pragma unroll
      for (int j = 0; j < 4; ++j)
        s += fmaxf((acc[mi][ni][j] + bi) * scl + shf, 0.f);
    s += __shfl_xor(s, 16);
    s += __shfl_xor(s, 32);
    part[ni] = s;
  }
  if (lane < 16) {
#pragma unroll
    for (int ni = 0; ni < 4; ++ni)
      s_wp[wave * 64 + ni * 16 + lr] = part[ni];
  }
  __syncthreads();
  if (tid < 128) {
    const int w0 = tid >> 6, idx = tid & 63;
    const float v = s_wp[w0 * 64 + idx] + s_wp[(w0 + 2) * 64 + idx];
    atomicAdd(&pooled[(size_t)(gimg0 + img) * 6272 + tid * 49 + blockIdx.y * 7 + blockIdx.x],
              v * (1.f / 1024.f));
  }
}

// =====================================================================
// RPN head: feat NHWC [B,784,256]. 1x1 cls/reg + softmax + decode.
// =====================================================================
__global__ __launch_bounds__(256) void rpn_head_k(
    const float* __restrict__ feat,
    const float* __restrict__ clsw, const float* __restrict__ clsb,
    const float* __restrict__ regw, const float* __restrict__ regb,
    float* __restrict__ probs, float* __restrict__ boxes) {
  const int gid = blockIdx.x * 256 + threadIdx.x;
  if (gid >= 32 * NANCH) return;
  const int a = gid & 3;
  int r = gid >> 2;
  const int x = r % 28; r /= 28;
  const int y = r % 28;
  const int b = r / 28;

  const float* f = feat + ((size_t)b * 784 + y * 28 + x) * 256;
  float c0 = clsb[2 * a], c1 = clsb[2 * a + 1];
  float r0 = regb[4 * a], r1 = regb[4 * a + 1], r2 = regb[4 * a + 2], r3 = regb[4 * a + 3];
#pragma unroll 4
  for (int c = 0; c < 256; c++) {
    const float fv = f[c];
    c0 = fmaf(fv, clsw[(2 * a) * 256 + c], c0);
    c1 = fmaf(fv, clsw[(2 * a + 1) * 256 + c], c1);
    r0 = fmaf(fv, regw[(4 * a) * 256 + c], r0);
    r1 = fmaf(fv, regw[(4 * a + 1) * 256 + c], r1);
    r2 = fmaf(fv, regw[(4 * a + 2) * 256 + c], r2);
    r3 = fmaf(fv, regw[(4 * a + 3) * 256 + c], r3);
  }
  const float p = 1.f / (1.f + expf(c0 - c1));

  const float cx = (x + 0.5f) * (1.f / 28.f);
  const float cy = (y + 0.5f) * (1.f / 28.f);
  const float sz = (float)(16 << a) * (1.f / 224.f);
  const float ncx = cx + r0 * 0.1f, ncy = cy + r1 * 0.1f;
  const float nw = sz * expf(r2 * 0.2f), nh = sz * expf(r3 * 0.2f);
  const float x1 = fminf(fmaxf(ncx - nw * 0.5f, 0.f), 1.f);
  const float y1 = fminf(fmaxf(ncy - nh * 0.5f, 0.f), 1.f);
  const float x2 = fminf(fmaxf(ncx + nw * 0.5f, 0.f), 1.f);
  const float y2 = fminf(fmaxf(ncy + nh * 0.5f, 0.f), 1.f);

  probs[gid] = p;
  ((float4*)boxes)[gid] = make_float4(x1, y1, x2, y2);
}

// =====================================================================
// Greedy NMS, one block per image (matches jax.lax.scan semantics).
// =====================================================================
__global__ __launch_bounds__(256) void nms_k(
    const float* __restrict__ probs, const float* __restrict__ boxes,
    float* __restrict__ dout, int* __restrict__ hasflag) {
  const int b = blockIdx.x;
  const int t = threadIdx.x;
  __shared__ float sc[NANCH];
  __shared__ float ar[NANCH];
  __shared__ float4 bx[NANCH];
  __shared__ float rv[256];
  __shared__ int   ri[256];
  __shared__ int s_any, s_sel[MAXP], s_ok[MAXP];

  if (t == 0) s_any = 0;
  __syncthreads();

  int anyl = 0;
  for (int i = t; i < NANCH; i += 256) {
    const float p = probs[(size_t)b * NANCH + i];
    const float4 bb = ((const float4*)boxes)[(size_t)b * NANCH + i];
    bx[i] = bb;
    ar[i] = (bb.z - bb.x) * (bb.w - bb.y);
    sc[i] = (p > SCORE_T) ? p : -INFINITY;
    if (p > SCORE_T) anyl = 1;
  }
  if (anyl) atomicOr(&s_any, 1);
  __syncthreads();

  for (int it = 0; it < MAXP; ++it) {
    float bv = -INFINITY; int bi = 0x7fffffff;
    for (int i = t; i < NANCH; i += 256) {
      const float v = sc[i];
      if (v > bv || (v == bv && i < bi)) { bv = v; bi = i; }
    }
    rv[t] = bv; ri[t] = bi;
    __syncthreads();
    for (int st = 128; st > 0; st >>= 1) {
      if (t < st) {
        const float ov = rv[t + st]; const int oi = ri[t + st];
        if (ov > rv[t] || (ov == rv[t] && oi < ri[t])) { rv[t] = ov; ri[t] = oi; }
      }
      __syncthreads();
    }
    if (t == 0) { s_sel[it] = ri[0]; s_ok[it] = (rv[0] > -INFINITY) ? 1 : 0; }
    __syncthreads();
    const int sel = s_sel[it];
    const int ok  = s_ok[it];
    if (ok) {
      const float4 bs = bx[sel]; const float as = ar[sel];
      for (int i = t; i < NANCH; i += 256) {
        const float xx1 = fmaxf(bs.x, bx[i].x), yy1 = fmaxf(bs.y, bx[i].y);
        const float xx2 = fminf(bs.z, bx[i].z), yy2 = fminf(bs.w, bx[i].w);
        const float inter = fmaxf(xx2 - xx1, 0.f) * fmaxf(yy2 - yy1, 0.f);
        const float iou = inter / (as + ar[i] - inter);
        if (iou > IOU_T || i == sel) sc[i] = -INFINITY;
      }
    }
    __syncthreads();
  }

  if (t < MAXP) {
    const int sel = s_ok[t] ? s_sel[t] : 0;
    const float okf = s_ok[t] ? 1.f : 0.f;
    const float4 bb = bx[sel];
    float* kb = dout + 64;
    float* ks = dout + 64 + 32 * MAXP * 4;
    float* ko = dout + 64 + 32 * MAXP * 5;
    const size_t base = ((size_t)b * MAXP + t) * 4;
    kb[base + 0] = bb.x * okf; kb[base + 1] = bb.y * okf;
    kb[base + 2] = bb.z * okf; kb[base + 3] = bb.w * okf;
    ks[b * MAXP + t] = probs[(size_t)b * NANCH + sel] * okf;
    ko[b * MAXP + t] = okf;
  }
  if (t == 0) hasflag[b] = s_any;
}

// =====================================================================
// FC split-K: weights read exactly once across the grid.
// =====================================================================
__global__ __launch_bounds__(64) void fcsplit_k(
    const float* __restrict__ x, const float* __restrict__ w,
    float* __restrict__ part, int K, int N, int kchunk) {
  extern __shared__ float sx[];
  const int o = blockIdx.x * 64 + threadIdx.x;
  const int k0 = blockIdx.y * kchunk;
  for (int i = threadIdx.x; i < 32 * kchunk; i += 64) {
    const int bb = i / kchunk, kk = i % kchunk;
    sx[i] = x[(size_t)bb * K + k0 + kk];
  }
  __syncthreads();
  float acc[32];
#pragma unroll
  for (int bb = 0; bb < 32; bb++) acc[bb] = 0.f;
#pragma unroll 8
  for (int kk = 0; kk < kchunk; kk++) {
    const float wv = w[(size_t)(k0 + kk) * N + o];
#pragma unroll
    for (int bb = 0; bb < 32; bb++) acc[bb] = fmaf(sx[bb * kchunk + kk], wv, acc[bb]);
  }
  float* p = part + (size_t)blockIdx.y * 32 * N + o;
#pragma unroll
  for (int bb = 0; bb < 32; bb++) p[(size_t)bb * N] = acc[bb];
}

__global__ __launch_bounds__(256) void fcreduce_k(
    const float* __restrict__ part, const float* __restrict__ bias,
    float* __restrict__ y, int N, int KT, int dorelu) {
  const int i = blockIdx.x * 256 + threadIdx.x;
  if (i >= 32 * N) return;
  const int o = i % N;
  float s = bias[o];
  for (int kt = 0; kt < KT; kt++) s += part[(size_t)kt * 32 * N + i];
  y[i] = dorelu ? fmaxf(s, 0.f) : s;
}

__global__ __launch_bounds__(64) void final_k(
    const float* __restrict__ f3, const float* __restrict__ w,
    const float* __restrict__ bi, const int* __restrict__ hasflag,
    float* __restrict__ dout) {
  const int t = threadIdx.x;
  if (t >= 64) return;
  const int b = t >> 1, j = t & 1;
  float acc = bi[j];
#pragma unroll 4
  for (int k = 0; k < 128; k++) acc = fmaf(f3[b * 128 + k], w[k * 2 + j], acc);
  dout[b * 2 + j] = hasflag[b] ? acc : (j == 0 ? 1.f : 0.f);
}

// =====================================================================
extern "C" void kernel_launch(void* const* d_in, const int* in_sizes, int n_in,
                              void* d_out, int out_size, void* d_ws, size_t ws_size,
                              hipStream_t stream) {
  const float* x    = (const float*)d_in[0];
  const float* r1w  = (const float*)d_in[1];  const float* r1b = (const float*)d_in[2];
  const float* g1   = (const float*)d_in[3];  const float* b1  = (const float*)d_in[4];
  const float* r2w  = (const float*)d_in[5];  const float* r2b = (const float*)d_in[6];
  const float* g2   = (const float*)d_in[7];  const float* b2  = (const float*)d_in[8];
  const float* r3w  = (const float*)d_in[9];  const float* r3b = (const float*)d_in[10];
  const float* g3   = (const float*)d_in[11]; const float* b3  = (const float*)d_in[12];
  const float* rpw  = (const float*)d_in[13]; const float* rpb = (const float*)d_in[14];
  const float* clsw = (const float*)d_in[15]; const float* clsb = (const float*)d_in[16];
  const float* regw = (const float*)d_in[17]; const float* regb = (const float*)d_in[18];
  const float* c1w  = (const float*)d_in[19]; const float* c1b = (const float*)d_in[20];
  const float* cg1  = (const float*)d_in[21]; const float* cb1 = (const float*)d_in[22];
  const float* c2w  = (const float*)d_in[23]; const float* c2b = (const float*)d_in[24];
  const float* cg2  = (const float*)d_in[25]; const float* cb2 = (const float*)d_in[26];
  const float* fc1w = (const float*)d_in[27]; const float* fc1b = (const float*)d_in[28];
  const float* fc2w = (const float*)d_in[29]; const float* fc2b = (const float*)d_in[30];
  const float* fc3w = (const float*)d_in[31]; const float* fc3b = (const float*)d_in[32];
  const float* fc4w = (const float*)d_in[33]; const float* fc4b = (const float*)d_in[34];
  float* dout = (float*)d_out;
  float* Wp = (float*)d_ws;

  // ---- workspace layout (float slots) ----
  const size_t o_h1   = 0;                      // hi/lo NHWC 32x112x112x32: 2x12.85M shorts
  const size_t o_h2   = 12845056;               // hi/lo NHWC 32x56x56x64
  const size_t o_h3   = o_h2 + 6422528;         // hi/lo NHWC 32x28x28x128
  const size_t o_prob = o_h3 + 3211264;
  const size_t o_box  = o_prob + 100352;
  const size_t o_flag = o_box + 401408;
  const size_t o_pool = o_flag + 32;
  const size_t o_f1   = o_pool + 200704;
  const size_t o_f2   = o_f1 + 16384;
  const size_t o_f3   = o_f2 + 8192;
  const size_t o_w2b  = o_f3 + 4096;            // 73728 shorts (CLM c2 bf16)
  const size_t o_w2s  = o_w2b + 36864;          // conv2 hi+lo: 2x18432 shorts
  const size_t o_w3s  = o_w2s + 18432;          // conv3 hi+lo: 2x73728 shorts
  const size_t o_wps  = o_w3s + 73728;          // rpw  hi+lo: 2x294912 shorts
  const size_t o_w1r  = o_wps + 294912;         // rpn conv1 [32][64] hi+lo: 2x2048 shorts
  const size_t o_w1c  = o_w1r + 2048;           // clm c1 [64][64] hi+lo: 2x4096 shorts

  u16* h1hi = (u16*)(Wp + o_h1); u16* h1lo = h1hi + 12845056;
  u16* h2hi = (u16*)(Wp + o_h2); u16* h2lo = h2hi + 6422528;
  u16* h3hi = (u16*)(Wp + o_h3); u16* h3lo = h3hi + 3211264;
  float* probs = Wp + o_prob; float* boxes = Wp + o_box;
  int* hasflag = (int*)(Wp + o_flag);
  float* pooled = Wp + o_pool;
  float* f1 = Wp + o_f1; float* f2 = Wp + o_f2; float* f3 = Wp + o_f3;
  u16* w2b  = (u16*)(Wp + o_w2b);
  u16* w2hi = (u16*)(Wp + o_w2s); u16* w2lo = w2hi + 18432;
  u16* w3hi = (u16*)(Wp + o_w3s); u16* w3lo = w3hi + 73728;
  u16* wphi = (u16*)(Wp + o_wps); u16* wplo = wphi + 294912;
  u16* w1rhi = (u16*)(Wp + o_w1r); u16* w1rlo = w1rhi + 2048;
  u16* w1chi = (u16*)(Wp + o_w1c); u16* w1clo = w1chi + 4096;
  // aliases over dead h1 region (safe by stream order):
  float* h4f32 = Wp + o_h1;            // rpn feat NHWC fp32 [32,784,256] = 6.42M
  u16*   c1buf = (u16*)(Wp + o_h1);    // CLM c1 NHWC bf16, 8 imgs = 25.69M shorts
  float* fcpart = Wp + o_h1;           // fc split partials (<= 1.05M)

  // ---- weight prep ----
  wsplit_k<<<(9 * 64 * 32 + 255) / 256, 256, 0, stream>>>(r2w, w2hi, w2lo, 64, 32);
  wsplit_k<<<(9 * 128 * 64 + 255) / 256, 256, 0, stream>>>(r3w, w3hi, w3lo, 128, 64);
  wsplit_k<<<(9 * 256 * 128 + 255) / 256, 256, 0, stream>>>(rpw, wphi, wplo, 256, 128);
  w2b_k<<<288, 256, 0, stream>>>(c2w, w2b);
  w1prep_k<<<8, 256, 0, stream>>>(r1w, w1rhi, w1rlo, 32);
  w1prep_k<<<16, 256, 0, stream>>>(c1w, w1chi, w1clo, 64);

  // ---- Stage 1: RPN backbone ----
  c1mfma_k<1><<<dim3(14, 56, 32), 256, 0, stream>>>(
      x, w1rhi, w1rlo, r1b, g1, b1, h1hi, h1lo);
  sconv_k<1, true, true><<<dim3(4, 28, 32), 256, 0, stream>>>(
      h1hi, h1lo, w2hi, w2lo, r2b, g2, b2, h2hi, h2lo, nullptr, 112, 112, 64, 1);
  sconv_k<2, true, true><<<dim3(2, 14, 64), 256, 0, stream>>>(
      h2hi, h2lo, w3hi, w3lo, r3b, g3, b3, h3hi, h3lo, nullptr, 56, 56, 128, 2);
  sconv_k<4, false, false><<<dim3(1, 7, 128), 256, 0, stream>>>(
      h3hi, h3lo, wphi, wplo, rpb, rpb, rpb, nullptr, nullptr, h4f32, 28, 28, 256, 4);

  rpn_head_k<<<(32 * NANCH + 255) / 256, 256, 0, stream>>>(h4f32, clsw, clsb, regw, regb, probs, boxes);
  nms_k<<<32, 256, 0, stream>>>(probs, boxes, dout, hasflag);

  // ---- Stage 2: CLM ----
  hipMemsetAsync(pooled, 0, 32 * 6272 * sizeof(float), stream);
  constexpr int CHUNK = 8;
  for (int c0 = 0; c0 < 32; c0 += CHUNK) {
    c1mfma_k<0><<<dim3(14, 56, CHUNK), 256, 0, stream>>>(
        x + (size_t)c0 * 4 * 224 * 224, w1chi, w1clo, c1b, cg1, cb1, c1buf, nullptr);
    c2band_k<<<dim3(7, 7, CHUNK * 8), 256, 0, stream>>>(
        c1buf, w2b, c2b, cg2, cb2, pooled, c0);
  }

  // ---- FC head ----
  fcsplit_k<<<dim3(8, 64), 64, 32 * 98 * 4, stream>>>(pooled, fc1w, fcpart, 6272, 512, 98);
  fcreduce_k<<<64, 256, 0, stream>>>(fcpart, fc1b, f1, 512, 64, 1);
  fcsplit_k<<<dim3(4, 16), 64, 32 * 32 * 4, stream>>>(f1, fc2w, fcpart, 512, 256, 32);
  fcreduce_k<<<32, 256, 0, stream>>>(fcpart, fc2b, f2, 256, 16, 1);
  fcsplit_k<<<dim3(2, 8), 64, 32 * 32 * 4, stream>>>(f2, fc3w, fcpart, 256, 128, 32);
  fcreduce_k<<<16, 256, 0, stream>>>(fcpart, fc3b, f3, 128, 8, 1);
  final_k<<<1, 64, 0, stream>>>(f3, fc4w, fc4b, hasflag, dout);
}